// Round 4
// baseline (145.773 us; speedup 1.0000x reference)
//
#include <hip/hip_runtime.h>

// OIM unsupervised loss, MI355X/gfx950 — round 4.
// R3 geometry (128x128 tile, 4 waves @64x64, mfma_f32_16x16x32_bf16, K=768
// hi/lo-compensated, fragment-linear operands, global_load_lds w=16) with the
// K-loop converted to T3+T4: 64KB double-buffered LDS, 2 phases per K-tile,
// issue-early staging, counted vmcnt(4) (never drained mid-loop), raw
// s_barrier with compiler memory fences, setprio(1) around MFMA clusters.

#define BT 4096
#define NPID 5000
#define FDIM 256
#define KAUG 768
#define NCHUNK 24        // KAUG / 32
#define BPROWS 10240
#define SIDE 5120
#define SCALE2 43.2808512266689f   // 30*log2(e)
#define LN2 0.6931471805599453f
#define PADMARK ((int)0x80000000)

typedef __attribute__((ext_vector_type(8))) short short8;
typedef __attribute__((ext_vector_type(4))) float f32x4;

__device__ __forceinline__ unsigned short f2bf_rne(float f) {
  unsigned int u = __float_as_uint(f);
  u += 0x7fffu + ((u >> 16) & 1u);
  return (unsigned short)(u >> 16);
}
__device__ __forceinline__ float bf2f(unsigned short h) {
  return __uint_as_float(((unsigned int)h) << 16);
}

// 16B-unit index of (row, oct) in 16x16x32 fragment-linear layout.
__device__ __forceinline__ size_t frag_unit(int row, int oct) {
  int c  = oct >> 2;   // 32-wide k-chunk
  int ko = oct & 3;    // 8-wide oct within chunk
  return ((size_t)(row >> 4) * NCHUNK + c) * 64 + (row & 15) + (ko << 4);
}

__global__ __launch_bounds__(256) void convert_A(const float* __restrict__ x,
                                                 unsigned short* __restrict__ outp) {
  int idx = blockIdx.x * 256 + threadIdx.x;
  if (idx >= BT * 96) return;
  int row = idx / 96, oct = idx % 96;
  int seg = oct >> 5;          // 0,1: hi   2: lo
  int so  = oct & 31;
  const float4* s4 = (const float4*)(x + (size_t)row * FDIM + so * 8);
  float4 f0 = s4[0], f1 = s4[1];
  float fv[8] = {f0.x, f0.y, f0.z, f0.w, f1.x, f1.y, f1.z, f1.w};
  short8 ov;
#pragma unroll
  for (int j = 0; j < 8; ++j) {
    unsigned short hi = f2bf_rne(fv[j]);
    if (seg == 2) hi = f2bf_rne(fv[j] - bf2f(hi));
    ov[j] = (short)hi;
  }
  *(short8*)(outp + frag_unit(row, oct) * 8) = ov;
}

__global__ __launch_bounds__(256) void convert_B(const float* __restrict__ lut,
                                                 const float* __restrict__ reid,
                                                 unsigned short* __restrict__ outp) {
  int idx = blockIdx.x * 256 + threadIdx.x;
  if (idx >= BPROWS * 96) return;
  int row = idx / 96, oct = idx % 96;
  int seg = oct >> 5;          // 0: hi  1: lo  2: hi
  int so  = oct & 31;
  const float* src = nullptr;
  if (row < NPID) src = lut + (size_t)row * FDIM + so * 8;
  else if (row >= SIDE && row < SIDE + NPID) src = reid + (size_t)(row - SIDE) * FDIM + so * 8;
  short8 ov;
  if (src) {
    const float4* s4 = (const float4*)src;
    float4 f0 = s4[0], f1 = s4[1];
    float fv[8] = {f0.x, f0.y, f0.z, f0.w, f1.x, f1.y, f1.z, f1.w};
#pragma unroll
    for (int j = 0; j < 8; ++j) {
      unsigned short hi = f2bf_rne(fv[j]);
      if (seg == 1) hi = f2bf_rne(fv[j] - bf2f(hi));
      ov[j] = (short)hi;
    }
  } else {
#pragma unroll
    for (int j = 0; j < 8; ++j) ov[j] = 0;
  }
  *(short8*)(outp + frag_unit(row, oct) * 8) = ov;
}

__global__ __launch_bounds__(256) void meta_fc(const float* __restrict__ inputs,
                                               const int* __restrict__ roi,
                                               const float* __restrict__ lut,
                                               const int* __restrict__ rlab,
                                               int* __restrict__ g, int* __restrict__ lr,
                                               float* __restrict__ w2f, float* __restrict__ v1f,
                                               float* __restrict__ fc) {
  int gt = blockIdx.x * 256 + threadIdx.x;
  int row = gt >> 6, lane = gt & 63;
  if (row >= BT) return;
  int t = roi[row] - 1;
  bool valid = t >= 0;
  int label = t > 0 ? t : 0;
  int gg = rlab[label];
  const float4* xv = (const float4*)(inputs + (size_t)row * FDIM);
  const float4* lv = (const float4*)(lut + (size_t)label * FDIM);
  float4 a = xv[lane], b = lv[lane];
  float dx = b.x - a.x, dy = b.y - a.y, dz = b.z - a.z, dw = b.w - a.w;
  float s = dx * dx + dy * dy + dz * dz + dw * dw;
#pragma unroll
  for (int d = 1; d < 64; d <<= 1) s += __shfl_xor(s, d, 64);
  if (lane == 0) {
    g[row]   = gg;
    lr[row]  = gg > 0 ? gg : 0;
    w2f[row] = (valid && gg >= 0) ? 1.0f : 0.0f;
    v1f[row] = valid ? 1.0f : 0.0f;
    fc[row]  = valid ? s : 0.0f;
  }
}

__global__ __launch_bounds__(256, 2) void gemm_main(const unsigned short* __restrict__ Ap,
                                                    const unsigned short* __restrict__ Bp,
                                                    const int* __restrict__ rlab,
                                                    const int* __restrict__ g,
                                                    const int* __restrict__ lr,
                                                    float* __restrict__ partials,
                                                    float* __restrict__ posbuf,
                                                    int* __restrict__ poscnt,
                                                    float* __restrict__ target) {
  __shared__ unsigned short lds[32768] __attribute__((aligned(16)));  // 64 KB, 2 buffers
  const int bid = blockIdx.x;
  const int xcd = bid & 7;
  const int i   = bid >> 3;
  const int cb  = i >> 2;              // 0..79 (0..39 inst, 40..79 reid)
  const int rb  = xcd * 4 + (i & 3);   // 0..31
  const int tid = threadIdx.x;
  const int l = tid & 63;
  const int w = tid >> 6;
  const int wr = w >> 1, wc = w & 1;

  f32x4 acc[4][4];
#pragma unroll
  for (int mi = 0; mi < 4; ++mi)
#pragma unroll
    for (int ni = 0; ni < 4; ++ni) acc[mi][ni] = (f32x4){0.f, 0.f, 0.f, 0.f};

  // half-tile A: 16 frag-blocks (cc*8+rg), 4 loads/thread. Same for B.
  auto issueA = [&](int t, int nb) {
#pragma unroll
    for (int j = 0; j < 4; ++j) {
      const int fa = j * 4 + w;          // 0..15
      const int cc = fa >> 3, rg = fa & 7;
      const unsigned short* src = Ap + ((size_t)((rb * 8 + rg) * NCHUNK + (t * 2 + cc)) << 9) + l * 8;
      unsigned short* dst = &lds[nb * 16384 + fa * 512];
      __builtin_amdgcn_global_load_lds((const __attribute__((address_space(1))) unsigned int*)src,
                                       (__attribute__((address_space(3))) unsigned int*)dst, 16, 0, 0);
    }
  };
  auto issueB = [&](int t, int nb) {
#pragma unroll
    for (int j = 0; j < 4; ++j) {
      const int fb = j * 4 + w;
      const int cc = fb >> 3, cg = fb & 7;
      const unsigned short* src = Bp + ((size_t)((cb * 8 + cg) * NCHUNK + (t * 2 + cc)) << 9) + l * 8;
      unsigned short* dst = &lds[nb * 16384 + 8192 + fb * 512];
      __builtin_amdgcn_global_load_lds((const __attribute__((address_space(1))) unsigned int*)src,
                                       (__attribute__((address_space(3))) unsigned int*)dst, 16, 0, 0);
    }
  };

  issueA(0, 0);
  issueB(0, 0);                          // 8 loads outstanding
  int cur = 0;
#pragma unroll 2
  for (int t = 0; t < 12; ++t) {
    const int nb = cur ^ 1;
    const bool pre = (t < 11);           // uniform branch
    // ---- phase 0 (cc = 0) ----
    if (pre) {
      issueA(t + 1, nb);                 // 12 outstanding
      asm volatile("s_waitcnt vmcnt(4)" ::: "memory");  // tile t's 8 loads done
    } else {
      asm volatile("s_waitcnt vmcnt(0)" ::: "memory");
    }
    asm volatile("s_barrier" ::: "memory");
    {
      const int bse = cur * 16384;
      short8 a0 = *(const short8*)&lds[bse + (wr * 4 + 0) * 512 + l * 8];
      short8 a1 = *(const short8*)&lds[bse + (wr * 4 + 1) * 512 + l * 8];
      short8 a2 = *(const short8*)&lds[bse + (wr * 4 + 2) * 512 + l * 8];
      short8 a3 = *(const short8*)&lds[bse + (wr * 4 + 3) * 512 + l * 8];
      short8 b0 = *(const short8*)&lds[bse + 8192 + (wc * 4 + 0) * 512 + l * 8];
      short8 b1 = *(const short8*)&lds[bse + 8192 + (wc * 4 + 1) * 512 + l * 8];
      short8 b2 = *(const short8*)&lds[bse + 8192 + (wc * 4 + 2) * 512 + l * 8];
      short8 b3 = *(const short8*)&lds[bse + 8192 + (wc * 4 + 3) * 512 + l * 8];
      __builtin_amdgcn_s_setprio(1);
      acc[0][0] = __builtin_amdgcn_mfma_f32_16x16x32_bf16(a0, b0, acc[0][0], 0, 0, 0);
      acc[0][1] = __builtin_amdgcn_mfma_f32_16x16x32_bf16(a0, b1, acc[0][1], 0, 0, 0);
      acc[0][2] = __builtin_amdgcn_mfma_f32_16x16x32_bf16(a0, b2, acc[0][2], 0, 0, 0);
      acc[0][3] = __builtin_amdgcn_mfma_f32_16x16x32_bf16(a0, b3, acc[0][3], 0, 0, 0);
      acc[1][0] = __builtin_amdgcn_mfma_f32_16x16x32_bf16(a1, b0, acc[1][0], 0, 0, 0);
      acc[1][1] = __builtin_amdgcn_mfma_f32_16x16x32_bf16(a1, b1, acc[1][1], 0, 0, 0);
      acc[1][2] = __builtin_amdgcn_mfma_f32_16x16x32_bf16(a1, b2, acc[1][2], 0, 0, 0);
      acc[1][3] = __builtin_amdgcn_mfma_f32_16x16x32_bf16(a1, b3, acc[1][3], 0, 0, 0);
      acc[2][0] = __builtin_amdgcn_mfma_f32_16x16x32_bf16(a2, b0, acc[2][0], 0, 0, 0);
      acc[2][1] = __builtin_amdgcn_mfma_f32_16x16x32_bf16(a2, b1, acc[2][1], 0, 0, 0);
      acc[2][2] = __builtin_amdgcn_mfma_f32_16x16x32_bf16(a2, b2, acc[2][2], 0, 0, 0);
      acc[2][3] = __builtin_amdgcn_mfma_f32_16x16x32_bf16(a2, b3, acc[2][3], 0, 0, 0);
      acc[3][0] = __builtin_amdgcn_mfma_f32_16x16x32_bf16(a3, b0, acc[3][0], 0, 0, 0);
      acc[3][1] = __builtin_amdgcn_mfma_f32_16x16x32_bf16(a3, b1, acc[3][1], 0, 0, 0);
      acc[3][2] = __builtin_amdgcn_mfma_f32_16x16x32_bf16(a3, b2, acc[3][2], 0, 0, 0);
      acc[3][3] = __builtin_amdgcn_mfma_f32_16x16x32_bf16(a3, b3, acc[3][3], 0, 0, 0);
      __builtin_amdgcn_s_setprio(0);
    }
    asm volatile("s_barrier" ::: "memory");
    // ---- phase 1 (cc = 1) ----
    if (pre) issueB(t + 1, nb);          // <=8 outstanding
    {
      const int bse = cur * 16384 + 8 * 512;   // cc=1 region offset for A
      short8 a0 = *(const short8*)&lds[bse + (wr * 4 + 0) * 512 + l * 8];
      short8 a1 = *(const short8*)&lds[bse + (wr * 4 + 1) * 512 + l * 8];
      short8 a2 = *(const short8*)&lds[bse + (wr * 4 + 2) * 512 + l * 8];
      short8 a3 = *(const short8*)&lds[bse + (wr * 4 + 3) * 512 + l * 8];
      short8 b0 = *(const short8*)&lds[bse + 8192 + (wc * 4 + 0) * 512 + l * 8];
      short8 b1 = *(const short8*)&lds[bse + 8192 + (wc * 4 + 1) * 512 + l * 8];
      short8 b2 = *(const short8*)&lds[bse + 8192 + (wc * 4 + 2) * 512 + l * 8];
      short8 b3 = *(const short8*)&lds[bse + 8192 + (wc * 4 + 3) * 512 + l * 8];
      __builtin_amdgcn_s_setprio(1);
      acc[0][0] = __builtin_amdgcn_mfma_f32_16x16x32_bf16(a0, b0, acc[0][0], 0, 0, 0);
      acc[0][1] = __builtin_amdgcn_mfma_f32_16x16x32_bf16(a0, b1, acc[0][1], 0, 0, 0);
      acc[0][2] = __builtin_amdgcn_mfma_f32_16x16x32_bf16(a0, b2, acc[0][2], 0, 0, 0);
      acc[0][3] = __builtin_amdgcn_mfma_f32_16x16x32_bf16(a0, b3, acc[0][3], 0, 0, 0);
      acc[1][0] = __builtin_amdgcn_mfma_f32_16x16x32_bf16(a1, b0, acc[1][0], 0, 0, 0);
      acc[1][1] = __builtin_amdgcn_mfma_f32_16x16x32_bf16(a1, b1, acc[1][1], 0, 0, 0);
      acc[1][2] = __builtin_amdgcn_mfma_f32_16x16x32_bf16(a1, b2, acc[1][2], 0, 0, 0);
      acc[1][3] = __builtin_amdgcn_mfma_f32_16x16x32_bf16(a1, b3, acc[1][3], 0, 0, 0);
      acc[2][0] = __builtin_amdgcn_mfma_f32_16x16x32_bf16(a2, b0, acc[2][0], 0, 0, 0);
      acc[2][1] = __builtin_amdgcn_mfma_f32_16x16x32_bf16(a2, b1, acc[2][1], 0, 0, 0);
      acc[2][2] = __builtin_amdgcn_mfma_f32_16x16x32_bf16(a2, b2, acc[2][2], 0, 0, 0);
      acc[2][3] = __builtin_amdgcn_mfma_f32_16x16x32_bf16(a2, b3, acc[2][3], 0, 0, 0);
      acc[3][0] = __builtin_amdgcn_mfma_f32_16x16x32_bf16(a3, b0, acc[3][0], 0, 0, 0);
      acc[3][1] = __builtin_amdgcn_mfma_f32_16x16x32_bf16(a3, b1, acc[3][1], 0, 0, 0);
      acc[3][2] = __builtin_amdgcn_mfma_f32_16x16x32_bf16(a3, b2, acc[3][2], 0, 0, 0);
      acc[3][3] = __builtin_amdgcn_mfma_f32_16x16x32_bf16(a3, b3, acc[3][3], 0, 0, 0);
      __builtin_amdgcn_s_setprio(0);
    }
    asm volatile("s_barrier" ::: "memory");  // protects buf[nb] overwrite next iter
    cur ^= 1;
  }

  // ---- epilogue: max-free exp2 sums (logits bounded by |43.3| in base-2) ----
  const bool inst = cb < 40;
  const int cbl = inst ? cb : cb - 40;
  int scol[4], rl4[4];
#pragma unroll
  for (int nr = 0; nr < 4; ++nr) {
    scol[nr] = cbl * 128 + wc * 64 + nr * 16 + (l & 15);     // side-local col
    rl4[nr] = (inst && scol[nr] < NPID) ? rlab[scol[nr]] : PADMARK;
  }
  const int rowbase = rb * 128 + wr * 64 + ((l >> 4) << 2);
  const int chunk = (inst ? 0 : 80) + cbl * 2 + wc;

#pragma unroll
  for (int mr = 0; mr < 4; ++mr) {
#pragma unroll
    for (int reg = 0; reg < 4; ++reg) {
      const int row = rowbase + mr * 16 + reg;
      float s = 0.f;
      if (inst) {
        const int gv = g[row];
#pragma unroll
        for (int nr = 0; nr < 4; ++nr) {
          float x2 = acc[mr][nr][reg] * SCALE2;
          bool pos = (rl4[nr] == gv);
          if (pos) {
            int idx = atomicAdd(&poscnt[row], 1);
            if (idx < 16) posbuf[row * 16 + idx] = x2;
          }
          if (!pos && rl4[nr] != PADMARK) s += exp2f(x2);
        }
      } else {
        const int lrv = lr[row];
#pragma unroll
        for (int nr = 0; nr < 4; ++nr) {
          float x2 = acc[mr][nr][reg] * SCALE2;
          if (scol[nr] == lrv) target[row] = x2;
          if (scol[nr] < NPID) s += exp2f(x2);
        }
      }
#pragma unroll
      for (int d = 1; d < 16; d <<= 1) s += __shfl_xor(s, d, 64);
      if ((l & 15) == 0) partials[(size_t)chunk * BT + row] = s;
    }
  }
}

__global__ __launch_bounds__(256) void combine(const float* __restrict__ partials,
                                               const float* __restrict__ posbuf,
                                               const int* __restrict__ poscnt,
                                               const float* __restrict__ target,
                                               const float* __restrict__ w2f,
                                               float* __restrict__ Lrow,
                                               float* __restrict__ Crow) {
  int row = blockIdx.x * 256 + threadIdx.x;
  if (row >= BT) return;
  float S = 0.f;
  for (int i = 0; i < 80; ++i) S += partials[(size_t)i * BT + row];
  float lse2n = __log2f(S);                 // base-2 lse of negatives
  int cnt = poscnt[row];
  int cc = cnt < 16 ? cnt : 16;
  float sum = 0.f;
  for (int j = 0; j < cc; ++j) {
    float d = LN2 * (lse2n - posbuf[row * 16 + j]);
    sum += (d > 60.f) ? d : log1pf(__expf(d));
  }
  float w2 = w2f[row];
  Lrow[row] = w2 * (sum / fmaxf((float)cnt, 1.0f));
  float S2 = 0.f;
  for (int i = 80; i < 160; ++i) S2 += partials[(size_t)i * BT + row];
  Crow[row] = w2 * LN2 * (__log2f(S2) - target[row]);
}

__global__ __launch_bounds__(256) void finalize(const float* __restrict__ fc,
                                                const float* __restrict__ v1f,
                                                const float* __restrict__ w2f,
                                                const float* __restrict__ Lrow,
                                                const float* __restrict__ Crow,
                                                float* __restrict__ out) {
  int t = threadIdx.x;
  float s0 = 0, s1 = 0, s2 = 0, s3 = 0, s4 = 0;
  for (int r = t; r < BT; r += 256) {
    s0 += fc[r]; s1 += v1f[r]; s2 += w2f[r]; s3 += Lrow[r]; s4 += Crow[r];
  }
#pragma unroll
  for (int d = 1; d < 64; d <<= 1) {
    s0 += __shfl_xor(s0, d, 64);
    s1 += __shfl_xor(s1, d, 64);
    s2 += __shfl_xor(s2, d, 64);
    s3 += __shfl_xor(s3, d, 64);
    s4 += __shfl_xor(s4, d, 64);
  }
  __shared__ float red[4][5];
  int lane = t & 63, wv = t >> 6;
  if (lane == 0) { red[wv][0] = s0; red[wv][1] = s1; red[wv][2] = s2; red[wv][3] = s3; red[wv][4] = s4; }
  __syncthreads();
  if (t == 0) {
    float a0 = 0, a1 = 0, a2 = 0, a3 = 0, a4 = 0;
    for (int i = 0; i < 4; ++i) { a0 += red[i][0]; a1 += red[i][1]; a2 += red[i][2]; a3 += red[i][3]; a4 += red[i][4]; }
    float n1 = fmaxf(a1, 1.0f);
    float n2 = fmaxf(a2, 1.0f);
    out[0] = a0 / (n1 * (float)FDIM) + a4 / n2 + a3 / n2;
  }
}

extern "C" void kernel_launch(void* const* d_in, const int* in_sizes, int n_in,
                              void* d_out, int out_size, void* d_ws, size_t ws_size,
                              hipStream_t stream) {
  const float* inputs = (const float*)d_in[0];
  const int*   roi    = (const int*)d_in[1];
  const float* lut    = (const float*)d_in[2];
  const float* reid   = (const float*)d_in[3];
  const int*   rlab   = (const int*)d_in[4];
  float* out = (float*)d_out;

  char* w = (char*)d_ws;
  unsigned short* Ap = (unsigned short*)(w);                 // 6,291,456 B
  unsigned short* Bp = (unsigned short*)(w + 6291456);       // 15,728,640 B -> 22,020,096
  float* partials    = (float*)(w + 22020096);               // 2,621,440 B  -> 24,641,536
  float* posbuf      = (float*)(w + 24641536);               // 262,144 B    -> 24,903,680
  int*   poscnt      = (int*)(w + 24903680);                 // 16,384 B     -> 24,920,064
  float* target      = (float*)(w + 24920064);               // 16,384 B     -> 24,936,448
  int*   g           = (int*)(w + 24936448);                 // 16,384 B     -> 24,952,832
  int*   lr          = (int*)(w + 24952832);                 // 16,384 B     -> 24,969,216
  float* w2f         = (float*)(w + 24969216);               // 16,384 B     -> 24,985,600
  float* v1f         = (float*)(w + 24985600);               // 16,384 B     -> 25,001,984
  float* fc          = (float*)(w + 25001984);               // 16,384 B     -> 25,018,368
  float* Lrow        = (float*)(w + 25018368);               // 16,384 B     -> 25,034,752
  float* Crow        = (float*)(w + 25034752);               // 16,384 B     -> 25,051,136

  hipMemsetAsync(poscnt, 0, BT * sizeof(int), stream);
  convert_A<<<(BT * 96 + 255) / 256, 256, 0, stream>>>(inputs, Ap);
  convert_B<<<(BPROWS * 96 + 255) / 256, 256, 0, stream>>>(lut, reid, Bp);
  meta_fc<<<(BT * 64) / 256, 256, 0, stream>>>(inputs, roi, lut, rlab, g, lr, w2f, v1f, fc);
  gemm_main<<<2560, 256, 0, stream>>>(Ap, Bp, rlab, g, lr, partials, posbuf, poscnt, target);
  combine<<<BT / 256, 256, 0, stream>>>(partials, posbuf, poscnt, target, w2f, Lrow, Crow);
  finalize<<<1, 256, 0, stream>>>(fc, v1f, w2f, Lrow, Crow, out);
}

// Round 5
// 92.036 us; speedup vs baseline: 1.5839x; 1.5839x over previous
//
#include <hip/hip_runtime.h>

// OIM unsupervised loss, MI355X/gfx950 — round 5.
// Plain f16 GEMM (K=256, no hi/lo augmentation): logits are 30*cosine of
// unit vectors; f16 quantization gives ~1e-3 logit error -> ~1e-4 final-loss
// error (rel ~5e-6). 3x less MFMA + staging than the bf16-compensated path.
// Structure = R3's proven m97 loop: 128x128 tile, 4 waves @64x64,
// mfma_f32_16x16x32_f16, BK=64 (4 steps), single-buffer 32KB LDS,
// global_load_lds w=16, fragment-linear operands, max-free exp2 epilogue,
// XCD-bijective rb-fast swizzle.

#define BT 4096
#define NPID 5000
#define FDIM 256
#define NCHUNK 8         // FDIM / 32
#define BPROWS 10240
#define SIDE 5120
#define SCALE2 43.2808512266689f   // 30*log2(e)
#define LN2 0.6931471805599453f
#define PADMARK ((int)0x80000000)

typedef __attribute__((ext_vector_type(8))) _Float16 half8;
typedef __attribute__((ext_vector_type(4))) float f32x4;

// 16B-unit index of (row, oct) in 16x16x32 fragment-linear layout.
// frag-block = 16 rows x 32 k = 1KB; lane = (row&15) + 16*(k>>3).
__device__ __forceinline__ size_t frag_unit(int row, int oct) {
  int c  = oct >> 2;   // 32-wide k-chunk (0..7)
  int ko = oct & 3;    // 8-wide oct within chunk
  return ((size_t)(row >> 4) * NCHUNK + c) * 64 + (row & 15) + (ko << 4);
}

__global__ __launch_bounds__(256) void convert_A(const float* __restrict__ x,
                                                 _Float16* __restrict__ outp) {
  int idx = blockIdx.x * 256 + threadIdx.x;
  if (idx >= BT * 32) return;
  int row = idx >> 5, oct = idx & 31;
  const float4* s4 = (const float4*)(x + (size_t)row * FDIM + oct * 8);
  float4 f0 = s4[0], f1 = s4[1];
  float fv[8] = {f0.x, f0.y, f0.z, f0.w, f1.x, f1.y, f1.z, f1.w};
  half8 ov;
#pragma unroll
  for (int j = 0; j < 8; ++j) ov[j] = (_Float16)fv[j];
  *(half8*)(outp + frag_unit(row, oct) * 8) = ov;
}

__global__ __launch_bounds__(256) void convert_B(const float* __restrict__ lut,
                                                 const float* __restrict__ reid,
                                                 _Float16* __restrict__ outp) {
  int idx = blockIdx.x * 256 + threadIdx.x;
  if (idx >= BPROWS * 32) return;
  int row = idx >> 5, oct = idx & 31;
  const float* src = nullptr;
  if (row < NPID) src = lut + (size_t)row * FDIM + oct * 8;
  else if (row >= SIDE && row < SIDE + NPID) src = reid + (size_t)(row - SIDE) * FDIM + oct * 8;
  half8 ov;
  if (src) {
    const float4* s4 = (const float4*)src;
    float4 f0 = s4[0], f1 = s4[1];
    float fv[8] = {f0.x, f0.y, f0.z, f0.w, f1.x, f1.y, f1.z, f1.w};
#pragma unroll
    for (int j = 0; j < 8; ++j) ov[j] = (_Float16)fv[j];
  } else {
#pragma unroll
    for (int j = 0; j < 8; ++j) ov[j] = (_Float16)0.f;
  }
  *(half8*)(outp + frag_unit(row, oct) * 8) = ov;
}

__global__ __launch_bounds__(256) void meta_fc(const float* __restrict__ inputs,
                                               const int* __restrict__ roi,
                                               const float* __restrict__ lut,
                                               const int* __restrict__ rlab,
                                               int* __restrict__ g, int* __restrict__ lr,
                                               float* __restrict__ w2f, float* __restrict__ v1f,
                                               float* __restrict__ fc) {
  int gt = blockIdx.x * 256 + threadIdx.x;
  int row = gt >> 6, lane = gt & 63;
  if (row >= BT) return;
  int t = roi[row] - 1;
  bool valid = t >= 0;
  int label = t > 0 ? t : 0;
  int gg = rlab[label];
  const float4* xv = (const float4*)(inputs + (size_t)row * FDIM);
  const float4* lv = (const float4*)(lut + (size_t)label * FDIM);
  float4 a = xv[lane], b = lv[lane];
  float dx = b.x - a.x, dy = b.y - a.y, dz = b.z - a.z, dw = b.w - a.w;
  float s = dx * dx + dy * dy + dz * dz + dw * dw;
#pragma unroll
  for (int d = 1; d < 64; d <<= 1) s += __shfl_xor(s, d, 64);
  if (lane == 0) {
    g[row]   = gg;
    lr[row]  = gg > 0 ? gg : 0;
    w2f[row] = (valid && gg >= 0) ? 1.0f : 0.0f;
    v1f[row] = valid ? 1.0f : 0.0f;
    fc[row]  = valid ? s : 0.0f;
  }
}

__global__ __launch_bounds__(256, 3) void gemm_main(const _Float16* __restrict__ Ap,
                                                    const _Float16* __restrict__ Bp,
                                                    const int* __restrict__ rlab,
                                                    const int* __restrict__ g,
                                                    const int* __restrict__ lr,
                                                    float* __restrict__ partials,
                                                    float* __restrict__ posbuf,
                                                    int* __restrict__ poscnt,
                                                    float* __restrict__ target) {
  __shared__ unsigned short lds[16384] __attribute__((aligned(16)));  // 32 KB
  // XCD-bijective, rb-fast swizzle: 2560 = 8 xcd * (80 cb * 4 rbl).
  const int bid = blockIdx.x;
  const int xcd = bid & 7;
  const int i   = bid >> 3;
  const int cb  = i >> 2;              // 0..79 (0..39 inst, 40..79 reid)
  const int rb  = xcd * 4 + (i & 3);   // 0..31
  const int tid = threadIdx.x;
  const int l = tid & 63;
  const int w = tid >> 6;
  const int wr = w >> 1, wc = w & 1;

  f32x4 acc[4][4];
#pragma unroll
  for (int mi = 0; mi < 4; ++mi)
#pragma unroll
    for (int ni = 0; ni < 4; ++ni) acc[mi][ni] = (f32x4){0.f, 0.f, 0.f, 0.f};

  for (int s = 0; s < 4; ++s) {            // K-steps of 64 (2 mfma chunks)
    const int c0 = s * 2;
    __syncthreads();
#pragma unroll
    for (int q = 0; q < 8; ++q) {          // 32 frag-blocks of 1KB, 8 per wave
      const int f = w * 8 + q;
      const bool isA = f < 16;
      const int fl = isA ? f : f - 16;
      const int cc = fl >> 3;
      const int grp = fl & 7;
      const int gidx = isA ? (rb * 8 + grp) : (cb * 8 + grp);
      const _Float16* src = (isA ? Ap : Bp)
          + (((size_t)gidx * NCHUNK + (c0 + cc)) << 6) * 8 + l * 8;
      unsigned short* dst = &lds[f * 512];
      __builtin_amdgcn_global_load_lds((const __attribute__((address_space(1))) unsigned int*)src,
                                       (__attribute__((address_space(3))) unsigned int*)dst,
                                       16, 0, 0);
    }
    __syncthreads();
#pragma unroll
    for (int cc = 0; cc < 2; ++cc) {
      half8 af[4], bfr[4];
#pragma unroll
      for (int mr = 0; mr < 4; ++mr)
        af[mr] = *(const half8*)&lds[(cc * 8 + (wr * 4 + mr)) * 512 + l * 8];
#pragma unroll
      for (int nr = 0; nr < 4; ++nr)
        bfr[nr] = *(const half8*)&lds[8192 + (cc * 8 + (wc * 4 + nr)) * 512 + l * 8];
#pragma unroll
      for (int mr = 0; mr < 4; ++mr)
#pragma unroll
        for (int nr = 0; nr < 4; ++nr)
          acc[mr][nr] = __builtin_amdgcn_mfma_f32_16x16x32_f16(af[mr], bfr[nr], acc[mr][nr], 0, 0, 0);
    }
  }

  // ---- epilogue: max-free exp2 sums (logits bounded by |43.3| in base-2) ----
  const bool inst = cb < 40;
  const int cbl = inst ? cb : cb - 40;
  int scol[4], rl4[4];
#pragma unroll
  for (int nr = 0; nr < 4; ++nr) {
    scol[nr] = cbl * 128 + wc * 64 + nr * 16 + (l & 15);     // side-local col
    rl4[nr] = (inst && scol[nr] < NPID) ? rlab[scol[nr]] : PADMARK;
  }
  const int rowbase = rb * 128 + wr * 64 + ((l >> 4) << 2);
  const int chunk = (inst ? 0 : 80) + cbl * 2 + wc;

#pragma unroll
  for (int mr = 0; mr < 4; ++mr) {
#pragma unroll
    for (int reg = 0; reg < 4; ++reg) {
      const int row = rowbase + mr * 16 + reg;
      float s = 0.f;
      if (inst) {
        const int gv = g[row];
#pragma unroll
        for (int nr = 0; nr < 4; ++nr) {
          float x2 = acc[mr][nr][reg] * SCALE2;
          bool pos = (rl4[nr] == gv);
          if (pos) {
            int idx = atomicAdd(&poscnt[row], 1);
            if (idx < 16) posbuf[row * 16 + idx] = x2;
          }
          if (!pos && rl4[nr] != PADMARK) s += exp2f(x2);
        }
      } else {
        const int lrv = lr[row];
#pragma unroll
        for (int nr = 0; nr < 4; ++nr) {
          float x2 = acc[mr][nr][reg] * SCALE2;
          if (scol[nr] == lrv) target[row] = x2;
          if (scol[nr] < NPID) s += exp2f(x2);
        }
      }
#pragma unroll
      for (int d = 1; d < 16; d <<= 1) s += __shfl_xor(s, d, 64);
      if ((l & 15) == 0) partials[(size_t)chunk * BT + row] = s;
    }
  }
}

__global__ __launch_bounds__(256) void combine(const float* __restrict__ partials,
                                               const float* __restrict__ posbuf,
                                               const int* __restrict__ poscnt,
                                               const float* __restrict__ target,
                                               const float* __restrict__ w2f,
                                               float* __restrict__ Lrow,
                                               float* __restrict__ Crow) {
  int row = blockIdx.x * 256 + threadIdx.x;
  if (row >= BT) return;
  float S = 0.f;
  for (int i = 0; i < 80; ++i) S += partials[(size_t)i * BT + row];
  float lse2n = __log2f(S);                 // base-2 lse of negatives
  int cnt = poscnt[row];
  int cc = cnt < 16 ? cnt : 16;
  float sum = 0.f;
  for (int j = 0; j < cc; ++j) {
    float d = LN2 * (lse2n - posbuf[row * 16 + j]);
    sum += (d > 60.f) ? d : log1pf(__expf(d));
  }
  float w2 = w2f[row];
  Lrow[row] = w2 * (sum / fmaxf((float)cnt, 1.0f));
  float S2 = 0.f;
  for (int i = 80; i < 160; ++i) S2 += partials[(size_t)i * BT + row];
  Crow[row] = w2 * LN2 * (__log2f(S2) - target[row]);
}

__global__ __launch_bounds__(256) void finalize(const float* __restrict__ fc,
                                                const float* __restrict__ v1f,
                                                const float* __restrict__ w2f,
                                                const float* __restrict__ Lrow,
                                                const float* __restrict__ Crow,
                                                float* __restrict__ out) {
  int t = threadIdx.x;
  float s0 = 0, s1 = 0, s2 = 0, s3 = 0, s4 = 0;
  for (int r = t; r < BT; r += 256) {
    s0 += fc[r]; s1 += v1f[r]; s2 += w2f[r]; s3 += Lrow[r]; s4 += Crow[r];
  }
#pragma unroll
  for (int d = 1; d < 64; d <<= 1) {
    s0 += __shfl_xor(s0, d, 64);
    s1 += __shfl_xor(s1, d, 64);
    s2 += __shfl_xor(s2, d, 64);
    s3 += __shfl_xor(s3, d, 64);
    s4 += __shfl_xor(s4, d, 64);
  }
  __shared__ float red[4][5];
  int lane = t & 63, wv = t >> 6;
  if (lane == 0) { red[wv][0] = s0; red[wv][1] = s1; red[wv][2] = s2; red[wv][3] = s3; red[wv][4] = s4; }
  __syncthreads();
  if (t == 0) {
    float a0 = 0, a1 = 0, a2 = 0, a3 = 0, a4 = 0;
    for (int i = 0; i < 4; ++i) { a0 += red[i][0]; a1 += red[i][1]; a2 += red[i][2]; a3 += red[i][3]; a4 += red[i][4]; }
    float n1 = fmaxf(a1, 1.0f);
    float n2 = fmaxf(a2, 1.0f);
    out[0] = a0 / (n1 * (float)FDIM) + a4 / n2 + a3 / n2;
  }
}

extern "C" void kernel_launch(void* const* d_in, const int* in_sizes, int n_in,
                              void* d_out, int out_size, void* d_ws, size_t ws_size,
                              hipStream_t stream) {
  const float* inputs = (const float*)d_in[0];
  const int*   roi    = (const int*)d_in[1];
  const float* lut    = (const float*)d_in[2];
  const float* reid   = (const float*)d_in[3];
  const int*   rlab   = (const int*)d_in[4];
  float* out = (float*)d_out;

  char* w = (char*)d_ws;
  _Float16* Ap    = (_Float16*)(w);                  // 2,097,152 B
  _Float16* Bp    = (_Float16*)(w + 2097152);        // 5,242,880 B  -> 7,340,032
  float* partials = (float*)(w + 7340032);           // 2,621,440 B  -> 9,961,472
  float* posbuf   = (float*)(w + 9961472);           // 262,144 B    -> 10,223,616
  int*   poscnt   = (int*)(w + 10223616);            // 16,384 B     -> 10,240,000
  float* target   = (float*)(w + 10240000);          // 16,384 B     -> 10,256,384
  int*   g        = (int*)(w + 10256384);            // 16,384 B     -> 10,272,768
  int*   lr       = (int*)(w + 10272768);            // 16,384 B     -> 10,289,152
  float* w2f      = (float*)(w + 10289152);          // 16,384 B     -> 10,305,536
  float* v1f      = (float*)(w + 10305536);          // 16,384 B     -> 10,321,920
  float* fc       = (float*)(w + 10321920);          // 16,384 B     -> 10,338,304
  float* Lrow     = (float*)(w + 10338304);          // 16,384 B     -> 10,354,688
  float* Crow     = (float*)(w + 10354688);          // 16,384 B     -> 10,371,072

  hipMemsetAsync(poscnt, 0, BT * sizeof(int), stream);
  convert_A<<<(BT * 32 + 255) / 256, 256, 0, stream>>>(inputs, Ap);
  convert_B<<<(BPROWS * 32 + 255) / 256, 256, 0, stream>>>(lut, reid, Bp);
  meta_fc<<<(BT * 64) / 256, 256, 0, stream>>>(inputs, roi, lut, rlab, g, lr, w2f, v1f, fc);
  gemm_main<<<2560, 256, 0, stream>>>(Ap, Bp, rlab, g, lr, partials, posbuf, poscnt, target);
  combine<<<BT / 256, 256, 0, stream>>>(partials, posbuf, poscnt, target, w2f, Lrow, Crow);
  finalize<<<1, 256, 0, stream>>>(fc, v1f, w2f, Lrow, Crow, out);
}

// Round 6
// 79.439 us; speedup vs baseline: 1.8350x; 1.1586x over previous
//
#include <hip/hip_runtime.h>

// OIM unsupervised loss, MI355X/gfx950 — round 6.
// R5 (f16 K=256, m97-structure 128x128 tile) with SWAPPED-OPERAND MFMA:
// compute C^T = mfma(Bfrag, Afrag) so each lane owns one output row and 16
// consecutive output cols -> row-sum is lane-local; cross-lane merge is 2
// shfl_xor per row (was 4 per row-reg). Epilogue E ~61us -> ~27us predicted.

#define BT 4096
#define NPID 5000
#define FDIM 256
#define NCHUNK 8         // FDIM / 32
#define BPROWS 10240
#define SIDE 5120
#define SCALE2 43.2808512266689f   // 30*log2(e)
#define LN2 0.6931471805599453f
#define PADMARK ((int)0x80000000)

typedef __attribute__((ext_vector_type(8))) _Float16 half8;
typedef __attribute__((ext_vector_type(4))) float f32x4;

// 16B-unit index of (row, oct) in 16x16x32 fragment-linear layout.
// frag-block = 16 rows x 32 k = 1KB; lane = (row&15) + 16*(k>>3).
__device__ __forceinline__ size_t frag_unit(int row, int oct) {
  int c  = oct >> 2;   // 32-wide k-chunk (0..7)
  int ko = oct & 3;    // 8-wide oct within chunk
  return ((size_t)(row >> 4) * NCHUNK + c) * 64 + (row & 15) + (ko << 4);
}

__global__ __launch_bounds__(256) void convert_A(const float* __restrict__ x,
                                                 _Float16* __restrict__ outp) {
  int idx = blockIdx.x * 256 + threadIdx.x;
  if (idx >= BT * 32) return;
  int row = idx >> 5, oct = idx & 31;
  const float4* s4 = (const float4*)(x + (size_t)row * FDIM + oct * 8);
  float4 f0 = s4[0], f1 = s4[1];
  float fv[8] = {f0.x, f0.y, f0.z, f0.w, f1.x, f1.y, f1.z, f1.w};
  half8 ov;
#pragma unroll
  for (int j = 0; j < 8; ++j) ov[j] = (_Float16)fv[j];
  *(half8*)(outp + frag_unit(row, oct) * 8) = ov;
}

__global__ __launch_bounds__(256) void convert_B(const float* __restrict__ lut,
                                                 const float* __restrict__ reid,
                                                 _Float16* __restrict__ outp) {
  int idx = blockIdx.x * 256 + threadIdx.x;
  if (idx >= BPROWS * 32) return;
  int row = idx >> 5, oct = idx & 31;
  const float* src = nullptr;
  if (row < NPID) src = lut + (size_t)row * FDIM + oct * 8;
  else if (row >= SIDE && row < SIDE + NPID) src = reid + (size_t)(row - SIDE) * FDIM + oct * 8;
  half8 ov;
  if (src) {
    const float4* s4 = (const float4*)src;
    float4 f0 = s4[0], f1 = s4[1];
    float fv[8] = {f0.x, f0.y, f0.z, f0.w, f1.x, f1.y, f1.z, f1.w};
#pragma unroll
    for (int j = 0; j < 8; ++j) ov[j] = (_Float16)fv[j];
  } else {
#pragma unroll
    for (int j = 0; j < 8; ++j) ov[j] = (_Float16)0.f;
  }
  *(half8*)(outp + frag_unit(row, oct) * 8) = ov;
}

__global__ __launch_bounds__(256) void meta_fc(const float* __restrict__ inputs,
                                               const int* __restrict__ roi,
                                               const float* __restrict__ lut,
                                               const int* __restrict__ rlab,
                                               int* __restrict__ g, int* __restrict__ lr,
                                               float* __restrict__ w2f, float* __restrict__ v1f,
                                               float* __restrict__ fc) {
  int gt = blockIdx.x * 256 + threadIdx.x;
  int row = gt >> 6, lane = gt & 63;
  if (row >= BT) return;
  int t = roi[row] - 1;
  bool valid = t >= 0;
  int label = t > 0 ? t : 0;
  int gg = rlab[label];
  const float4* xv = (const float4*)(inputs + (size_t)row * FDIM);
  const float4* lv = (const float4*)(lut + (size_t)label * FDIM);
  float4 a = xv[lane], b = lv[lane];
  float dx = b.x - a.x, dy = b.y - a.y, dz = b.z - a.z, dw = b.w - a.w;
  float s = dx * dx + dy * dy + dz * dz + dw * dw;
#pragma unroll
  for (int d = 1; d < 64; d <<= 1) s += __shfl_xor(s, d, 64);
  if (lane == 0) {
    g[row]   = gg;
    lr[row]  = gg > 0 ? gg : 0;
    w2f[row] = (valid && gg >= 0) ? 1.0f : 0.0f;
    v1f[row] = valid ? 1.0f : 0.0f;
    fc[row]  = valid ? s : 0.0f;
  }
}

__global__ __launch_bounds__(256, 3) void gemm_main(const _Float16* __restrict__ Ap,
                                                    const _Float16* __restrict__ Bp,
                                                    const int* __restrict__ rlab,
                                                    const int* __restrict__ g,
                                                    const int* __restrict__ lr,
                                                    float* __restrict__ partials,
                                                    float* __restrict__ posbuf,
                                                    int* __restrict__ poscnt,
                                                    float* __restrict__ target) {
  __shared__ unsigned short lds[16384] __attribute__((aligned(16)));  // 32 KB
  // XCD-bijective, rb-fast swizzle: 2560 = 8 xcd * (80 cb * 4 rbl).
  const int bid = blockIdx.x;
  const int xcd = bid & 7;
  const int i   = bid >> 3;
  const int cb  = i >> 2;              // 0..79 (0..39 inst, 40..79 reid)
  const int rb  = xcd * 4 + (i & 3);   // 0..31
  const int tid = threadIdx.x;
  const int l = tid & 63;
  const int w = tid >> 6;
  const int wr = w >> 1, wc = w & 1;

  // acc[mc][nr]: C^T fragments. mc indexes output-COL frags (B rows),
  // nr indexes output-ROW frags (A rows). Lane l: output row = nr*16+(l&15),
  // output cols = mc*16 + (l>>4)*4 + reg.
  f32x4 acc[4][4];
#pragma unroll
  for (int mi = 0; mi < 4; ++mi)
#pragma unroll
    for (int ni = 0; ni < 4; ++ni) acc[mi][ni] = (f32x4){0.f, 0.f, 0.f, 0.f};

  for (int s = 0; s < 4; ++s) {            // K-steps of 64 (2 mfma chunks)
    const int c0 = s * 2;
    __syncthreads();
#pragma unroll
    for (int q = 0; q < 8; ++q) {          // 32 frag-blocks of 1KB, 8 per wave
      const int f = w * 8 + q;
      const bool isA = f < 16;
      const int fl = isA ? f : f - 16;
      const int cc = fl >> 3;
      const int grp = fl & 7;
      const int gidx = isA ? (rb * 8 + grp) : (cb * 8 + grp);
      const _Float16* src = (isA ? Ap : Bp)
          + (((size_t)gidx * NCHUNK + (c0 + cc)) << 6) * 8 + l * 8;
      unsigned short* dst = &lds[f * 512];
      __builtin_amdgcn_global_load_lds((const __attribute__((address_space(1))) unsigned int*)src,
                                       (__attribute__((address_space(3))) unsigned int*)dst,
                                       16, 0, 0);
    }
    __syncthreads();
#pragma unroll
    for (int cc = 0; cc < 2; ++cc) {
      half8 cf[4], rf[4];
#pragma unroll
      for (int mc = 0; mc < 4; ++mc)       // col-frags from B region
        cf[mc] = *(const half8*)&lds[8192 + (cc * 8 + (wc * 4 + mc)) * 512 + l * 8];
#pragma unroll
      for (int nr = 0; nr < 4; ++nr)       // row-frags from A region
        rf[nr] = *(const half8*)&lds[(cc * 8 + (wr * 4 + nr)) * 512 + l * 8];
#pragma unroll
      for (int mc = 0; mc < 4; ++mc)
#pragma unroll
        for (int nr = 0; nr < 4; ++nr)
          acc[mc][nr] = __builtin_amdgcn_mfma_f32_16x16x32_f16(cf[mc], rf[nr], acc[mc][nr], 0, 0, 0);
    }
  }

  // ---- epilogue: lane-local row sums (C^T layout), 2 shfl per row ----
  const bool inst = cb < 40;
  const int cbl = inst ? cb : cb - 40;
  __syncthreads();
  int* rl_s = (int*)lds;                    // reuse LDS: 128 ints
  if (tid < 128) {
    int scol = cbl * 128 + tid;
    rl_s[tid] = (inst && scol < NPID) ? rlab[scol] : PADMARK;
  }
  __syncthreads();

  const int colg = l >> 4;                  // 0..3
  const int rlane = l & 15;
  int4 rlv[4];
#pragma unroll
  for (int mc = 0; mc < 4; ++mc)            // broadcast reads, no conflicts
    rlv[mc] = *(const int4*)&rl_s[wc * 64 + mc * 16 + colg * 4];

  const int chunk = (inst ? 0 : 80) + cbl * 2 + wc;
  const int rowb = rb * 128 + wr * 64 + rlane;

#pragma unroll
  for (int nr = 0; nr < 4; ++nr) {
    const int row = rowb + nr * 16;
    float s = 0.f;
    if (inst) {
      const int gv = g[row];
#pragma unroll
      for (int mc = 0; mc < 4; ++mc)
#pragma unroll
        for (int reg = 0; reg < 4; ++reg) {
          float x2 = acc[mc][nr][reg] * SCALE2;
          int rl = ((const int*)&rlv[mc])[reg];
          bool pos = (rl == gv);
          if (pos) {
            int idx = atomicAdd(&poscnt[row], 1);
            if (idx < 16) posbuf[row * 16 + idx] = x2;
          }
          if (!pos && rl != PADMARK) s += exp2f(x2);
        }
    } else {
      const int lrv = lr[row];
      const int sbase = cbl * 128 + wc * 64 + colg * 4;
#pragma unroll
      for (int mc = 0; mc < 4; ++mc)
#pragma unroll
        for (int reg = 0; reg < 4; ++reg) {
          int scol = sbase + mc * 16 + reg;
          float x2 = acc[mc][nr][reg] * SCALE2;
          if (scol == lrv) target[row] = x2;
          if (scol < NPID) s += exp2f(x2);
        }
    }
    s += __shfl_xor(s, 16, 64);
    s += __shfl_xor(s, 32, 64);
    if (colg == 0) partials[(size_t)chunk * BT + row] = s;
  }
}

__global__ __launch_bounds__(256) void combine(const float* __restrict__ partials,
                                               const float* __restrict__ posbuf,
                                               const int* __restrict__ poscnt,
                                               const float* __restrict__ target,
                                               const float* __restrict__ w2f,
                                               float* __restrict__ Lrow,
                                               float* __restrict__ Crow) {
  int row = blockIdx.x * 256 + threadIdx.x;
  if (row >= BT) return;
  float S = 0.f;
  for (int i = 0; i < 80; ++i) S += partials[(size_t)i * BT + row];
  float lse2n = __log2f(S);                 // base-2 lse of negatives
  int cnt = poscnt[row];
  int cc = cnt < 16 ? cnt : 16;
  float sum = 0.f;
  for (int j = 0; j < cc; ++j) {
    float d = LN2 * (lse2n - posbuf[row * 16 + j]);
    sum += (d > 60.f) ? d : log1pf(__expf(d));
  }
  float w2 = w2f[row];
  Lrow[row] = w2 * (sum / fmaxf((float)cnt, 1.0f));
  float S2 = 0.f;
  for (int i = 80; i < 160; ++i) S2 += partials[(size_t)i * BT + row];
  Crow[row] = w2 * LN2 * (__log2f(S2) - target[row]);
}

__global__ __launch_bounds__(256) void finalize(const float* __restrict__ fc,
                                                const float* __restrict__ v1f,
                                                const float* __restrict__ w2f,
                                                const float* __restrict__ Lrow,
                                                const float* __restrict__ Crow,
                                                float* __restrict__ out) {
  int t = threadIdx.x;
  float s0 = 0, s1 = 0, s2 = 0, s3 = 0, s4 = 0;
  for (int r = t; r < BT; r += 256) {
    s0 += fc[r]; s1 += v1f[r]; s2 += w2f[r]; s3 += Lrow[r]; s4 += Crow[r];
  }
#pragma unroll
  for (int d = 1; d < 64; d <<= 1) {
    s0 += __shfl_xor(s0, d, 64);
    s1 += __shfl_xor(s1, d, 64);
    s2 += __shfl_xor(s2, d, 64);
    s3 += __shfl_xor(s3, d, 64);
    s4 += __shfl_xor(s4, d, 64);
  }
  __shared__ float red[4][5];
  int lane = t & 63, wv = t >> 6;
  if (lane == 0) { red[wv][0] = s0; red[wv][1] = s1; red[wv][2] = s2; red[wv][3] = s3; red[wv][4] = s4; }
  __syncthreads();
  if (t == 0) {
    float a0 = 0, a1 = 0, a2 = 0, a3 = 0, a4 = 0;
    for (int i = 0; i < 4; ++i) { a0 += red[i][0]; a1 += red[i][1]; a2 += red[i][2]; a3 += red[i][3]; a4 += red[i][4]; }
    float n1 = fmaxf(a1, 1.0f);
    float n2 = fmaxf(a2, 1.0f);
    out[0] = a0 / (n1 * (float)FDIM) + a4 / n2 + a3 / n2;
  }
}

extern "C" void kernel_launch(void* const* d_in, const int* in_sizes, int n_in,
                              void* d_out, int out_size, void* d_ws, size_t ws_size,
                              hipStream_t stream) {
  const float* inputs = (const float*)d_in[0];
  const int*   roi    = (const int*)d_in[1];
  const float* lut    = (const float*)d_in[2];
  const float* reid   = (const float*)d_in[3];
  const int*   rlab   = (const int*)d_in[4];
  float* out = (float*)d_out;

  char* w = (char*)d_ws;
  _Float16* Ap    = (_Float16*)(w);                  // 2,097,152 B
  _Float16* Bp    = (_Float16*)(w + 2097152);        // 5,242,880 B  -> 7,340,032
  float* partials = (float*)(w + 7340032);           // 2,621,440 B  -> 9,961,472
  float* posbuf   = (float*)(w + 9961472);           // 262,144 B    -> 10,223,616
  int*   poscnt   = (int*)(w + 10223616);            // 16,384 B     -> 10,240,000
  float* target   = (float*)(w + 10240000);          // 16,384 B     -> 10,256,384
  int*   g        = (int*)(w + 10256384);            // 16,384 B     -> 10,272,768
  int*   lr       = (int*)(w + 10272768);            // 16,384 B     -> 10,289,152
  float* w2f      = (float*)(w + 10289152);          // 16,384 B     -> 10,305,536
  float* v1f      = (float*)(w + 10305536);          // 16,384 B     -> 10,321,920
  float* fc       = (float*)(w + 10321920);          // 16,384 B     -> 10,338,304
  float* Lrow     = (float*)(w + 10338304);          // 16,384 B     -> 10,354,688
  float* Crow     = (float*)(w + 10354688);          // 16,384 B     -> 10,371,072

  hipMemsetAsync(poscnt, 0, BT * sizeof(int), stream);
  convert_A<<<(BT * 32 + 255) / 256, 256, 0, stream>>>(inputs, Ap);
  convert_B<<<(BPROWS * 32 + 255) / 256, 256, 0, stream>>>(lut, reid, Bp);
  meta_fc<<<(BT * 64) / 256, 256, 0, stream>>>(inputs, roi, lut, rlab, g, lr, w2f, v1f, fc);
  gemm_main<<<2560, 256, 0, stream>>>(Ap, Bp, rlab, g, lr, partials, posbuf, poscnt, target);
  combine<<<BT / 256, 256, 0, stream>>>(partials, posbuf, poscnt, target, w2f, Lrow, Crow);
  finalize<<<1, 256, 0, stream>>>(fc, v1f, w2f, Lrow, Crow, out);
}